// Round 4
// baseline (346.273 us; speedup 1.0000x reference)
//
#include <hip/hip_runtime.h>

#define NB 128
#define NT 1024
#define NOBS 512
#define NH 64
#define NP 128
#define NM (NB*NT)      // 131072 rows
#define NN2 256         // 2*NP (re/im interleaved)
#define NCH 16          // chunks
#define CHL 64          // chunk length

typedef short bf16x8 __attribute__((ext_vector_type(8)));
typedef float f32x4 __attribute__((ext_vector_type(4)));

// ---- ws layout (bytes) ----
#define BU_OFF    ((size_t)0)              // 131072*256 bf16 = 67108864
#define AGGA_OFF  ((size_t)83886080)       // 128*16*128 float2 = 2097152
#define AGGB_OFF  ((size_t)85983232)       // 2097152
#define AGGC_OFF  ((size_t)88080384)       // 1048576
#define HIN_OFF   ((size_t)89128960)       // 2097152
#define CONST_OFF ((size_t)91226112)
#define CONST_STRIDE ((size_t)131072)
#define WTB_OFF   ((size_t)92274688)       // 512*64 bf16 = 65536 (dense W^T bf16)
// const block: [0,1024) lambar f32x2; [1024,33792) Bglob bf16 [256][64];
// [33792,66560) Cglob bf16 [64][256]; [66560,74752) gwT bf16 [64][64]

__device__ __forceinline__ unsigned short f2b(float f) {
  unsigned int u = __float_as_uint(f);
  u = u + 0x7fffu + ((u >> 16) & 1u);
  return (unsigned short)(u >> 16);
}
__device__ __forceinline__ float b2f(unsigned short s) {
  return __uint_as_float(((unsigned int)s) << 16);
}

// ---------------- setup: per-layer constant tables + dense W^T bf16 ----------------
__global__ __launch_bounds__(256) void k_setup(const float* Lre, const float* Lim,
    const float* Bp, const float* Cp, const float* lstep, const float* gw,
    const float* dw, unsigned char* wsb) {
  int l = blockIdx.y;
  int idx = blockIdx.x * 256 + threadIdx.x;   // [0,16384)
  unsigned char* cb = wsb + CONST_OFF + (size_t)l * CONST_STRIDE;
  float2* lambar = (float2*)cb;
  unsigned short* Bglob = (unsigned short*)(cb + 1024);
  unsigned short* Cglob = (unsigned short*)(cb + 33792);
  unsigned short* gwT   = (unsigned short*)(cb + 66560);
  {
    int n = idx >> 6, h = idx & 63, p = n >> 1, c = n & 1;
    float step = expf(lstep[l * NP + p]);
    float re = Lre[l * NP + p], im = Lim[l * NP + p];
    float er = expf(re * step), ang = im * step;
    float lbr = er * cosf(ang), lbi = er * sinf(ang);
    if (h == 0 && c == 0) lambar[p] = make_float2(lbr, lbi);
    float den = re * re + im * im;
    float nr = lbr - 1.f, ni = lbi;
    float dr = (nr * re + ni * im) / den;
    float di = (ni * re - nr * im) / den;
    size_t bb = ((size_t)(l * NP + p) * NH + h) * 2;
    float b0 = Bp[bb + 0], b1 = Bp[bb + 1];
    float vr = dr * b0 - di * b1;
    float vi = dr * b1 + di * b0;
    Bglob[n * 64 + h] = f2b(c ? vi : vr);
  }
  {
    int h = idx >> 8, n = idx & 255, p = n >> 1;
    size_t base = ((size_t)(l * NH + h) * NP + p) * 2;
    float val = (n & 1) ? (-2.f * Cp[base + 1]) : (2.f * Cp[base + 0]);
    Cglob[h * 256 + n] = f2b(val);
  }
  if (idx < 4096) {
    int n = idx >> 6, k = idx & 63;
    gwT[n * 64 + k] = f2b(gw[(size_t)(l * NH + k) * NH + n]);
  }
  {
    // dense W^T bf16: wTb[h][k] = bf16(dw[k][h]); 32768 elems over both l-blocks
    int idx2 = l * 16384 + idx;
    int h = idx2 >> 9, k = idx2 & 511;
    ((unsigned short*)(wsb + WTB_OFF))[h * 512 + k] = f2b(dw[(size_t)k * NH + h]);
  }
}

// ---------------- dense: x = obs @ W + b (pipelined, BK=64) ----------------
__global__ __launch_bounds__(256) void k_dense(const float* __restrict__ obs,
    const unsigned short* __restrict__ wTb, const float* __restrict__ bias,
    float* __restrict__ xout) {
  __shared__ __align__(16) unsigned short As[128][72];
  __shared__ __align__(16) unsigned short Bs[64][72];
  int tid = threadIdx.x, lane = tid & 63, wv = tid >> 6;
  int row0 = blockIdx.x * 128;
  f32x4 acc[2][4] = {};
  float bcol[4];
#pragma unroll
  for (int ct = 0; ct < 4; ++ct) bcol[ct] = bias[ct * 16 + (lane & 15)];
  float4 ra[8];
  uint4 rb[2];
  // preload k-tile 0
#pragma unroll
  for (int i = 0; i < 8; ++i) {
    int id = tid + i * 256;
    ra[i] = *(const float4*)(obs + (size_t)(row0 + (id >> 4)) * NOBS + (id & 15) * 4);
  }
#pragma unroll
  for (int i = 0; i < 2; ++i) {
    int id = tid + i * 256;
    rb[i] = *(const uint4*)(wTb + (id >> 3) * 512 + (id & 7) * 8);
  }
  for (int kt = 0; kt < 8; ++kt) {
    // write staged regs -> LDS
#pragma unroll
    for (int i = 0; i < 8; ++i) {
      int id = tid + i * 256;
      ushort4 o; o.x = f2b(ra[i].x); o.y = f2b(ra[i].y); o.z = f2b(ra[i].z); o.w = f2b(ra[i].w);
      *(ushort4*)&As[id >> 4][(id & 15) * 4] = o;
    }
#pragma unroll
    for (int i = 0; i < 2; ++i) {
      int id = tid + i * 256;
      *(uint4*)&Bs[id >> 3][(id & 7) * 8] = rb[i];
    }
    __syncthreads();
    // issue next tile's loads; they stay in flight across the MFMA phase
    if (kt < 7) {
      int k0 = (kt + 1) * 64;
#pragma unroll
      for (int i = 0; i < 8; ++i) {
        int id = tid + i * 256;
        ra[i] = *(const float4*)(obs + (size_t)(row0 + (id >> 4)) * NOBS + k0 + (id & 15) * 4);
      }
#pragma unroll
      for (int i = 0; i < 2; ++i) {
        int id = tid + i * 256;
        rb[i] = *(const uint4*)(wTb + (id >> 3) * 512 + k0 + (id & 7) * 8);
      }
    }
#pragma unroll
    for (int kc = 0; kc < 2; ++kc) {
      bf16x8 a0 = *(const bf16x8*)&As[wv * 32 + (lane & 15)][kc * 32 + (lane >> 4) * 8];
      bf16x8 a1 = *(const bf16x8*)&As[wv * 32 + 16 + (lane & 15)][kc * 32 + (lane >> 4) * 8];
#pragma unroll
      for (int ct = 0; ct < 4; ++ct) {
        bf16x8 bb = *(const bf16x8*)&Bs[ct * 16 + (lane & 15)][kc * 32 + (lane >> 4) * 8];
        acc[0][ct] = __builtin_amdgcn_mfma_f32_16x16x32_bf16(a0, bb, acc[0][ct], 0, 0, 0);
        acc[1][ct] = __builtin_amdgcn_mfma_f32_16x16x32_bf16(a1, bb, acc[1][ct], 0, 0, 0);
      }
    }
    __syncthreads();
  }
  // epilogue: 2-pass f32 bounce through LDS (aliases As)
  float* Os = (float*)&As[0][0];   // [64][68]
#pragma unroll
  for (int pass = 0; pass < 2; ++pass) {
    if ((wv >> 1) == pass) {
#pragma unroll
      for (int rt = 0; rt < 2; ++rt)
#pragma unroll
        for (int ct = 0; ct < 4; ++ct)
#pragma unroll
          for (int e = 0; e < 4; ++e) {
            int rl = (wv & 1) * 32 + rt * 16 + (lane >> 4) * 4 + e;
            int col = ct * 16 + (lane & 15);
            Os[rl * 68 + col] = acc[rt][ct][e] + bcol[ct];
          }
    }
    __syncthreads();
    {
      int r = tid >> 2, seg = tid & 3;
#pragma unroll
      for (int i = 0; i < 4; ++i)
        *(float4*)(xout + (size_t)(row0 + pass * 64 + r) * NH + seg * 16 + i * 4) =
            *(const float4*)&Os[r * 68 + seg * 16 + i * 4];
    }
    __syncthreads();
  }
}

// ---------------- fused: LN + Bu MFMA + chunk-aggregate scan (<=40KB LDS) ----------------
__global__ __launch_bounds__(256, 4) void k_lnbu_scan1(const float* __restrict__ x,
    const float* __restrict__ nsc, const float* __restrict__ nbi,
    const unsigned char* __restrict__ cb, const int* __restrict__ dones,
    unsigned short* __restrict__ bu,
    float2* __restrict__ aggA, float2* __restrict__ aggB, float* __restrict__ aggC) {
  __shared__ __align__(16) unsigned short BuS[64][264];
  __shared__ int dS[64];
  __shared__ float pA[256][2], pB[256][2], pC[256];
  unsigned short (*As)[72] = (unsigned short (*)[72])&BuS[0][0];   // alias: dead before BuS use
  int tid = threadIdx.x, lane = tid & 63, wv = tid >> 6;
  int row0 = blockIdx.x * 64;
  int b = blockIdx.x >> 4, ch = blockIdx.x & 15;
  const unsigned short* Bglob = (const unsigned short*)(cb + 1024);   // 32KB, L1-resident
  if (tid < 64) dS[tid] = dones[b * NT + ch * CHL + tid];
  // LayerNorm: 4 threads per row
  {
    int r = tid >> 2, q = tid & 3;
    const float* xr = x + (size_t)(row0 + r) * NH + q * 16;
    float4 vv[4];
#pragma unroll
    for (int i = 0; i < 4; ++i) vv[i] = *(const float4*)(xr + i * 4);
    const float* vp = (const float*)vv;
    float s = 0.f, s2 = 0.f;
#pragma unroll
    for (int j = 0; j < 16; ++j) { s += vp[j]; s2 += vp[j] * vp[j]; }
    s += __shfl_xor(s, 1); s2 += __shfl_xor(s2, 1);
    s += __shfl_xor(s, 2); s2 += __shfl_xor(s2, 2);
    float mu = s * 0.015625f;
    float var = s2 * 0.015625f - mu * mu;
    float rs = rsqrtf(var + 1e-6f);
#pragma unroll
    for (int j = 0; j < 16; ++j) {
      float xv = (vp[j] - mu) * rs * nsc[q * 16 + j] + nbi[q * 16 + j];
      As[r][q * 16 + j] = f2b(xv);
    }
  }
  __syncthreads();
  // Bu = xn @ Bbar^T (A from LDS, B fragments from L1-resident global table)
  f32x4 acc[16] = {};
#pragma unroll
  for (int kc = 0; kc < 2; ++kc) {
    bf16x8 a = *(const bf16x8*)&As[wv * 16 + (lane & 15)][kc * 32 + (lane >> 4) * 8];
#pragma unroll
    for (int ct = 0; ct < 16; ++ct) {
      bf16x8 bb = *(const bf16x8*)(Bglob + (ct * 16 + (lane & 15)) * 64 + kc * 32 + (lane >> 4) * 8);
      acc[ct] = __builtin_amdgcn_mfma_f32_16x16x32_bf16(a, bb, acc[ct], 0, 0, 0);
    }
  }
  __syncthreads();   // all As reads done; BuS may now overwrite the aliased region
#pragma unroll
  for (int ct = 0; ct < 16; ++ct)
#pragma unroll
    for (int e = 0; e < 4; ++e)
      BuS[wv * 16 + (lane >> 4) * 4 + e][ct * 16 + (lane & 15)] = f2b(acc[ct][e]);
  __syncthreads();
  // coalesced bounce LDS -> HBM
  {
    int r = tid >> 2, seg = tid & 3;
#pragma unroll
    for (int i = 0; i < 8; ++i)
      *(uint4*)(bu + (size_t)(row0 + r) * NN2 + seg * 64 + i * 8) =
          *(const uint4*)&BuS[r][seg * 64 + i * 8];
  }
  // chunk aggregate: 2 halves of 32 steps each
  {
    int p = tid & 127, half = tid >> 7;
    float2 lam = ((const float2*)cb)[p];
    float Ar = 1.f, Ai = 0.f, br = 0.f, bi = 0.f, c = 0.f;
    int t0 = half * 32;
#pragma unroll 4
    for (int i = 0; i < 32; ++i) {
      int t = t0 + i;
      unsigned int u = *(const unsigned int*)&BuS[t][2 * p];
      float bur = b2f((unsigned short)(u & 0xffffu));
      float bui = b2f((unsigned short)(u >> 16));
      if (dS[t]) { Ar = lam.x; Ai = lam.y; br = bur; bi = bui; c = 1.f; }
      else {
        float nAr = lam.x * Ar - lam.y * Ai; Ai = lam.x * Ai + lam.y * Ar; Ar = nAr;
        float nbr = lam.x * br - lam.y * bi + bur; bi = lam.x * bi + lam.y * br + bui; br = nbr;
      }
    }
    pA[tid][0] = Ar; pA[tid][1] = Ai; pB[tid][0] = br; pB[tid][1] = bi; pC[tid] = c;
  }
  __syncthreads();
  if (tid < 128) {
    float A0r = pA[tid][0], A0i = pA[tid][1], b0r = pB[tid][0], b0i = pB[tid][1], c0 = pC[tid];
    float A1r = pA[tid + 128][0], A1i = pA[tid + 128][1];
    float b1r = pB[tid + 128][0], b1i = pB[tid + 128][1], c1 = pC[tid + 128];
    float Ar, Ai, br, bi, c;
    if (c1 != 0.f) { Ar = A1r; Ai = A1i; br = b1r; bi = b1i; c = 1.f; }
    else {
      Ar = A1r * A0r - A1i * A0i; Ai = A1r * A0i + A1i * A0r;
      br = A1r * b0r - A1i * b0i + b1r; bi = A1r * b0i + A1i * b0r + b1i;
      c = c0;
    }
    int o = (b * NCH + ch) * NP + tid;
    aggA[o] = make_float2(Ar, Ai);
    aggB[o] = make_float2(br, bi);
    aggC[o] = c;
  }
}

// ---------------- scan chunks: cross-chunk prefix + h_out ----------------
__global__ __launch_bounds__(256) void k_scanchunks(const float* __restrict__ hidden,
    const float2* __restrict__ aggA, const float2* __restrict__ aggB,
    const float* __restrict__ aggC, float2* __restrict__ hin,
    float* __restrict__ hout, int l) {
  int gid = blockIdx.x * 256 + threadIdx.x;   // [0,16384)
  int b = gid >> 7, p = gid & 127;
  size_t hoff = ((size_t)(l * NB + b) * NP + p) * 2;
  float hr = hidden[hoff], hi = hidden[hoff + 1];
  for (int ch = 0; ch < NCH; ++ch) {
    int o = (b * NCH + ch) * NP + p;
    hin[o] = make_float2(hr, hi);
    float2 A = aggA[o]; float2 bb = aggB[o]; float c = aggC[o];
    if (c != 0.f) { hr = bb.x; hi = bb.y; }
    else {
      float nr = A.x * hr - A.y * hi + bb.x;
      hi = A.x * hi + A.y * hr + bb.y; hr = nr;
    }
  }
  hout[hoff] = hr; hout[hoff + 1] = hi;
}

// ---------------- fused: scan2 (in LDS) + ys + gelu + glu + residual (<=40KB LDS) ----------------
__global__ __launch_bounds__(256, 4) void k_ysglu_scan2(const unsigned short* __restrict__ bu,
    const int* __restrict__ dones, const unsigned char* __restrict__ cb,
    const float2* __restrict__ hin,
    const float* __restrict__ nsc, const float* __restrict__ nbi,
    const float* __restrict__ Dv, const float* __restrict__ gb,
    float* __restrict__ x) {
  __shared__ __align__(16) unsigned short BuS[64][264];
  __shared__ float muS[64], rsS[64];
  __shared__ int dS[64];
  unsigned short (*Ys)[72] = (unsigned short (*)[72])&BuS[0][0];       // 9.2KB, after ys-MFMA
  float* Os = (float*)((char*)&BuS[0][0] + 16384);                      // 16.9KB, disjoint from Ys
  int tid = threadIdx.x, lane = tid & 63, wv = tid >> 6;
  int row0 = blockIdx.x * 64;
  int b = blockIdx.x >> 4, ch = blockIdx.x & 15;
  const unsigned short* Cglob = (const unsigned short*)(cb + 33792);   // 32KB, L1-resident
  const unsigned short* gwT = (const unsigned short*)(cb + 66560);     // 8KB, L1-resident
  // load bu tile -> LDS
  {
    int r = tid >> 2, seg = tid & 3;
#pragma unroll
    for (int i = 0; i < 8; ++i)
      *(uint4*)&BuS[r][seg * 64 + i * 8] =
          *(const uint4*)(bu + (size_t)(row0 + r) * NN2 + seg * 64 + i * 8);
  }
  if (tid < 64) dS[tid] = dones[b * NT + ch * CHL + tid];
  float2 hseed;
  if (tid < 128) hseed = hin[(b * NCH + ch) * NP + tid];
  // preload x fragments (residual + LN re-apply)
  float xreg[4][4];
#pragma unroll
  for (int ct = 0; ct < 4; ++ct)
#pragma unroll
    for (int e = 0; e < 4; ++e) {
      int rl = wv * 16 + (lane >> 4) * 4 + e;
      xreg[ct][e] = x[(size_t)(row0 + rl) * NH + ct * 16 + (lane & 15)];
    }
  // LN stats: 4 threads per row
  {
    int r = tid >> 2, q = tid & 3;
    const float* xr = x + (size_t)(row0 + r) * NH + q * 16;
    float4 vv[4];
#pragma unroll
    for (int i = 0; i < 4; ++i) vv[i] = *(const float4*)(xr + i * 4);
    const float* vp = (const float*)vv;
    float s = 0.f, s2 = 0.f;
#pragma unroll
    for (int j = 0; j < 16; ++j) { s += vp[j]; s2 += vp[j] * vp[j]; }
    s += __shfl_xor(s, 1); s2 += __shfl_xor(s2, 1);
    s += __shfl_xor(s, 2); s2 += __shfl_xor(s2, 2);
    float mu = s * 0.015625f;
    float var = s2 * 0.015625f - mu * mu;
    if (q == 0) { muS[r] = mu; rsS[r] = rsqrtf(var + 1e-6f); }
  }
  __syncthreads();
  // scan2 in LDS: 128 chains, 64 steps, xs overwrites Bu in LDS
  if (tid < 128) {
    int p = tid;
    float2 lam = ((const float2*)cb)[p];
    float hr = hseed.x, hi = hseed.y;
#pragma unroll 4
    for (int t = 0; t < CHL; ++t) {
      unsigned int u = *(const unsigned int*)&BuS[t][2 * p];
      float bur = b2f((unsigned short)(u & 0xffffu));
      float bui = b2f((unsigned short)(u >> 16));
      if (dS[t]) { hr = bur; hi = bui; }
      else {
        float nr = lam.x * hr - lam.y * hi + bur;
        hi = lam.x * hi + lam.y * hr + bui; hr = nr;
      }
      *(unsigned int*)&BuS[t][2 * p] = (unsigned int)f2b(hr) | ((unsigned int)f2b(hi) << 16);
    }
  }
  __syncthreads();
  // ys = xs @ C^T (A from LDS, B fragments from L1-resident global table)
  f32x4 acc[4] = {};
#pragma unroll
  for (int kc = 0; kc < 8; ++kc) {
    bf16x8 a = *(const bf16x8*)&BuS[wv * 16 + (lane & 15)][kc * 32 + (lane >> 4) * 8];
#pragma unroll
    for (int ct = 0; ct < 4; ++ct) {
      bf16x8 bb = *(const bf16x8*)(Cglob + (ct * 16 + (lane & 15)) * 256 + kc * 32 + (lane >> 4) * 8);
      acc[ct] = __builtin_amdgcn_mfma_f32_16x16x32_bf16(a, bb, acc[ct], 0, 0, 0);
    }
  }
  __syncthreads();   // BuS reads done; Ys/Os aliases become writable
  // y = gelu(ys + D*xn), xn recomputed in f32; tanh via overflow-safe exp form
  float yreg[4][4];
#pragma unroll
  for (int ct = 0; ct < 4; ++ct)
#pragma unroll
    for (int e = 0; e < 4; ++e) {
      int rl = wv * 16 + (lane >> 4) * 4 + e;
      int col = ct * 16 + (lane & 15);
      float xnv = (xreg[ct][e] - muS[rl]) * rsS[rl] * nsc[col] + nbi[col];
      float yv = acc[ct][e] + Dv[col] * xnv;
      float t3 = 0.7978845608f * (yv + 0.044715f * yv * yv * yv);
      float u = __expf(2.f * t3);
      float th = 1.f - 2.f / (u + 1.f);
      yv = 0.5f * yv * (1.f + th);
      yreg[ct][e] = yv;
      Ys[rl][col] = f2b(yv);
    }
  __syncthreads();
  // GLU gate matmul (B fragments from L1-resident global table)
  f32x4 gacc[4] = {};
#pragma unroll
  for (int kc = 0; kc < 2; ++kc) {
    bf16x8 a = *(const bf16x8*)&Ys[wv * 16 + (lane & 15)][kc * 32 + (lane >> 4) * 8];
#pragma unroll
    for (int ct = 0; ct < 4; ++ct) {
      bf16x8 bb = *(const bf16x8*)(gwT + (ct * 16 + (lane & 15)) * 64 + kc * 32 + (lane >> 4) * 8);
      gacc[ct] = __builtin_amdgcn_mfma_f32_16x16x32_bf16(a, bb, gacc[ct], 0, 0, 0);
    }
  }
  // residual into Os (disjoint from Ys region still being read)
#pragma unroll
  for (int ct = 0; ct < 4; ++ct)
#pragma unroll
    for (int e = 0; e < 4; ++e) {
      int rl = wv * 16 + (lane >> 4) * 4 + e;
      int col = ct * 16 + (lane & 15);
      float g = gacc[ct][e] + gb[col];
      float s = 1.f / (1.f + __expf(-g));
      Os[rl * 66 + col] = xreg[ct][e] + yreg[ct][e] * s;
    }
  __syncthreads();
  {
    int r = tid >> 2, seg = tid & 3;
#pragma unroll
    for (int i = 0; i < 4; ++i)
      *(float4*)(x + (size_t)(row0 + r) * NH + seg * 16 + i * 4) =
          *(const float4*)&Os[r * 66 + seg * 16 + i * 4];
  }
}

extern "C" void kernel_launch(void* const* d_in, const int* in_sizes, int n_in,
                              void* d_out, int out_size, void* d_ws, size_t ws_size,
                              hipStream_t stream) {
  const float* obs    = (const float*)d_in[0];
  const int*   dones  = (const int*)d_in[1];
  const float* hidden = (const float*)d_in[2];
  const float* dw     = (const float*)d_in[3];
  const float* db     = (const float*)d_in[4];
  const float* Lre    = (const float*)d_in[5];
  const float* Lim    = (const float*)d_in[6];
  const float* Bp     = (const float*)d_in[7];
  const float* Cp     = (const float*)d_in[8];
  const float* Dv     = (const float*)d_in[9];
  const float* lstep  = (const float*)d_in[10];
  const float* nsc    = (const float*)d_in[11];
  const float* nbi    = (const float*)d_in[12];
  const float* gw     = (const float*)d_in[13];
  const float* gb     = (const float*)d_in[14];

  float* hout = (float*)d_out;
  float* x = hout + (size_t)2 * NB * NP * 2;   // 65536 floats offset

  unsigned char* wsb = (unsigned char*)d_ws;
  unsigned short* bu = (unsigned short*)(wsb + BU_OFF);
  float2* aggA = (float2*)(wsb + AGGA_OFF);
  float2* aggB = (float2*)(wsb + AGGB_OFF);
  float*  aggC = (float*)(wsb + AGGC_OFF);
  float2* hin  = (float2*)(wsb + HIN_OFF);
  unsigned short* wTb = (unsigned short*)(wsb + WTB_OFF);

  k_setup<<<dim3(64, 2), 256, 0, stream>>>(Lre, Lim, Bp, Cp, lstep, gw, dw, wsb);
  k_dense<<<NM / 128, 256, 0, stream>>>(obs, wTb, db, x);
  for (int l = 0; l < 2; ++l) {
    const unsigned char* cb = wsb + CONST_OFF + (size_t)l * CONST_STRIDE;
    k_lnbu_scan1<<<NM / 64, 256, 0, stream>>>(x, nsc + l * NH, nbi + l * NH, cb, dones,
                                              bu, aggA, aggB, aggC);
    k_scanchunks<<<NB * NP / 256, 256, 0, stream>>>(hidden, aggA, aggB, aggC, hin, hout, l);
    k_ysglu_scan2<<<NM / 64, 256, 0, stream>>>(bu, dones, cb, hin,
                                               nsc + l * NH, nbi + l * NH,
                                               Dv + l * NH, gb + l * NH, x);
  }
}

// Round 5
// 326.905 us; speedup vs baseline: 1.0592x; 1.0592x over previous
//
#include <hip/hip_runtime.h>

#define NB 128
#define NT 1024
#define NOBS 512
#define NH 64
#define NP 128
#define NM (NB*NT)      // 131072 rows
#define NN2 256
#define NCH 16
#define CHL 64

typedef short bf16x8 __attribute__((ext_vector_type(8)));
typedef float f32x4 __attribute__((ext_vector_type(4)));

// ---- ws layout (bytes) ----
#define CONST_OFF ((size_t)91226112)
#define CONST_STRIDE ((size_t)131072)
#define WTB_OFF   ((size_t)92274688)
// const block: [0,1024) lambar f32x2; [1024,33792) Bglob bf16 [256][64];
// [33792,66560) Cglob bf16 [64][256]; [66560,74752) gwT bf16 [64][64]

__device__ __forceinline__ unsigned short f2b(float f) {
  unsigned int u = __float_as_uint(f);
  u = u + 0x7fffu + ((u >> 16) & 1u);
  return (unsigned short)(u >> 16);
}
__device__ __forceinline__ float b2f(unsigned short s) {
  return __uint_as_float(((unsigned int)s) << 16);
}

// ---------------- setup: per-layer constant tables + dense W^T bf16 ----------------
__global__ __launch_bounds__(256) void k_setup(const float* Lre, const float* Lim,
    const float* Bp, const float* Cp, const float* lstep, const float* gw,
    const float* dw, unsigned char* wsb) {
  int l = blockIdx.y;
  int idx = blockIdx.x * 256 + threadIdx.x;   // [0,16384)
  unsigned char* cb = wsb + CONST_OFF + (size_t)l * CONST_STRIDE;
  float2* lambar = (float2*)cb;
  unsigned short* Bglob = (unsigned short*)(cb + 1024);
  unsigned short* Cglob = (unsigned short*)(cb + 33792);
  unsigned short* gwT   = (unsigned short*)(cb + 66560);
  {
    int n = idx >> 6, h = idx & 63, p = n >> 1, c = n & 1;
    float step = expf(lstep[l * NP + p]);
    float re = Lre[l * NP + p], im = Lim[l * NP + p];
    float er = expf(re * step), ang = im * step;
    float lbr = er * cosf(ang), lbi = er * sinf(ang);
    if (h == 0 && c == 0) lambar[p] = make_float2(lbr, lbi);
    float den = re * re + im * im;
    float nr = lbr - 1.f, ni = lbi;
    float dr = (nr * re + ni * im) / den;
    float di = (ni * re - nr * im) / den;
    size_t bb = ((size_t)(l * NP + p) * NH + h) * 2;
    float b0 = Bp[bb + 0], b1 = Bp[bb + 1];
    float vr = dr * b0 - di * b1;
    float vi = dr * b1 + di * b0;
    Bglob[n * 64 + h] = f2b(c ? vi : vr);
  }
  {
    int h = idx >> 8, n = idx & 255, p = n >> 1;
    size_t base = ((size_t)(l * NH + h) * NP + p) * 2;
    float val = (n & 1) ? (-2.f * Cp[base + 1]) : (2.f * Cp[base + 0]);
    Cglob[h * 256 + n] = f2b(val);
  }
  if (idx < 4096) {
    int n = idx >> 6, k = idx & 63;
    gwT[n * 64 + k] = f2b(gw[(size_t)(l * NH + k) * NH + n]);
  }
  {
    int idx2 = l * 16384 + idx;
    int h = idx2 >> 9, k = idx2 & 511;
    ((unsigned short*)(wsb + WTB_OFF))[h * 512 + k] = f2b(dw[(size_t)k * NH + h]);
  }
}

// ---------------- dense: x = obs @ W + b (pipelined, BK=64) ----------------
__global__ __launch_bounds__(256) void k_dense(const float* __restrict__ obs,
    const unsigned short* __restrict__ wTb, const float* __restrict__ bias,
    float* __restrict__ xout) {
  __shared__ __align__(16) unsigned short As[128][72];
  __shared__ __align__(16) unsigned short Bs[64][72];
  int tid = threadIdx.x, lane = tid & 63, wv = tid >> 6;
  int row0 = blockIdx.x * 128;
  f32x4 acc[2][4] = {};
  float bcol[4];
#pragma unroll
  for (int ct = 0; ct < 4; ++ct) bcol[ct] = bias[ct * 16 + (lane & 15)];
  float4 ra[8];
  uint4 rb[2];
#pragma unroll
  for (int i = 0; i < 8; ++i) {
    int id = tid + i * 256;
    ra[i] = *(const float4*)(obs + (size_t)(row0 + (id >> 4)) * NOBS + (id & 15) * 4);
  }
#pragma unroll
  for (int i = 0; i < 2; ++i) {
    int id = tid + i * 256;
    rb[i] = *(const uint4*)(wTb + (id >> 3) * 512 + (id & 7) * 8);
  }
  for (int kt = 0; kt < 8; ++kt) {
#pragma unroll
    for (int i = 0; i < 8; ++i) {
      int id = tid + i * 256;
      ushort4 o; o.x = f2b(ra[i].x); o.y = f2b(ra[i].y); o.z = f2b(ra[i].z); o.w = f2b(ra[i].w);
      *(ushort4*)&As[id >> 4][(id & 15) * 4] = o;
    }
#pragma unroll
    for (int i = 0; i < 2; ++i) {
      int id = tid + i * 256;
      *(uint4*)&Bs[id >> 3][(id & 7) * 8] = rb[i];
    }
    __syncthreads();
    if (kt < 7) {
      int k0 = (kt + 1) * 64;
#pragma unroll
      for (int i = 0; i < 8; ++i) {
        int id = tid + i * 256;
        ra[i] = *(const float4*)(obs + (size_t)(row0 + (id >> 4)) * NOBS + k0 + (id & 15) * 4);
      }
#pragma unroll
      for (int i = 0; i < 2; ++i) {
        int id = tid + i * 256;
        rb[i] = *(const uint4*)(wTb + (id >> 3) * 512 + k0 + (id & 7) * 8);
      }
    }
#pragma unroll
    for (int kc = 0; kc < 2; ++kc) {
      bf16x8 a0 = *(const bf16x8*)&As[wv * 32 + (lane & 15)][kc * 32 + (lane >> 4) * 8];
      bf16x8 a1 = *(const bf16x8*)&As[wv * 32 + 16 + (lane & 15)][kc * 32 + (lane >> 4) * 8];
#pragma unroll
      for (int ct = 0; ct < 4; ++ct) {
        bf16x8 bb = *(const bf16x8*)&Bs[ct * 16 + (lane & 15)][kc * 32 + (lane >> 4) * 8];
        acc[0][ct] = __builtin_amdgcn_mfma_f32_16x16x32_bf16(a0, bb, acc[0][ct], 0, 0, 0);
        acc[1][ct] = __builtin_amdgcn_mfma_f32_16x16x32_bf16(a1, bb, acc[1][ct], 0, 0, 0);
      }
    }
    __syncthreads();
  }
  float* Os = (float*)&As[0][0];   // [64][68]
#pragma unroll
  for (int pass = 0; pass < 2; ++pass) {
    if ((wv >> 1) == pass) {
#pragma unroll
      for (int rt = 0; rt < 2; ++rt)
#pragma unroll
        for (int ct = 0; ct < 4; ++ct)
#pragma unroll
          for (int e = 0; e < 4; ++e) {
            int rl = (wv & 1) * 32 + rt * 16 + (lane >> 4) * 4 + e;
            int col = ct * 16 + (lane & 15);
            Os[rl * 68 + col] = acc[rt][ct][e] + bcol[ct];
          }
    }
    __syncthreads();
    {
      int r = tid >> 2, seg = tid & 3;
#pragma unroll
      for (int i = 0; i < 4; ++i)
        *(float4*)(xout + (size_t)(row0 + pass * 64 + r) * NH + seg * 16 + i * 4) =
            *(const float4*)&Os[r * 68 + seg * 16 + i * 4];
    }
    __syncthreads();
  }
}

// ---------------- mega-fused per-layer kernel ----------------
// 1 block per batch b, 512 threads. Chunks processed sequentially with
// register-carried scan state; bu never touches global memory.
// Pipeline per iter i (3 barriers):
//   P1a: waves0-3 LN(i) -> xnS,murs | waves4-7 ysMFMA+GELU(i-2) -> Ys
//   P1b: waves4-7 GLU(i-2)+residual -> x
//   P2 : waves0-3 BuMFMA(i) -> BuS[i&1] | threads256-383 scan(i-1) on BuS[(i-1)&1]
__global__ __launch_bounds__(512, 2) void k_layer(float* __restrict__ x,
    const int* __restrict__ dones, const unsigned char* __restrict__ cb,
    const float* __restrict__ hidden, float* __restrict__ hout,
    const float* __restrict__ nsc, const float* __restrict__ nbi,
    const float* __restrict__ Dv, const float* __restrict__ gb, int l) {
  __shared__ __align__(16) unsigned short Bs[256][72];      // 36864
  __shared__ __align__(16) unsigned short Cs[64][264];      // 33792
  __shared__ __align__(16) unsigned short BuS[2][64][264];  // 67584
  __shared__ __align__(16) unsigned short xnS[64][72];      // 9216
  __shared__ __align__(16) unsigned short Ys[64][72];       // 9216
  __shared__ int dS[1024];                                  // 4096
  __shared__ float murs[4][64][2];                          // 2048  => 162816 B
  int tid = threadIdx.x, lane = tid & 63, wv = tid >> 6;
  int b = blockIdx.x;
  const unsigned short* Bglob = (const unsigned short*)(cb + 1024);
  const unsigned short* Cglob = (const unsigned short*)(cb + 33792);
  const unsigned short* gwT = (const unsigned short*)(cb + 66560);

  // stage tables
  {
    int r = tid >> 1, h0 = (tid & 1) * 32;
#pragma unroll
    for (int i = 0; i < 4; ++i)
      *(uint4*)&Bs[r][h0 + i * 8] = *(const uint4*)(Bglob + r * 64 + h0 + i * 8);
  }
  {
    int r = tid >> 3, s0 = (tid & 7) * 32;
#pragma unroll
    for (int i = 0; i < 4; ++i)
      *(uint4*)&Cs[r][s0 + i * 8] = *(const uint4*)(Cglob + r * 256 + s0 + i * 8);
  }
  dS[tid] = dones[b * NT + tid];
  dS[tid + 512] = dones[b * NT + 512 + tid];

  // role preloads
  float4 pre0, pre1, pre2, pre3;
  float nscr[16], nbir[16];
  float lamr = 0.f, lami = 0.f, hr = 0.f, hi = 0.f;
  float Dr[4], nscc[4], nbic[4], gbr[4];
  if (tid < 256) {
    int q = tid & 3;
#pragma unroll
    for (int j = 0; j < 16; ++j) { nscr[j] = nsc[q * 16 + j]; nbir[j] = nbi[q * 16 + j]; }
    int r = tid >> 2;
    const float* xr = x + ((size_t)b * NT + r) * NH + q * 16;
    pre0 = *(const float4*)(xr);     pre1 = *(const float4*)(xr + 4);
    pre2 = *(const float4*)(xr + 8); pre3 = *(const float4*)(xr + 12);
  } else {
#pragma unroll
    for (int ct = 0; ct < 4; ++ct) {
      int col = ct * 16 + (lane & 15);
      Dr[ct] = Dv[col]; nscc[ct] = nsc[col]; nbic[ct] = nbi[col]; gbr[ct] = gb[col];
    }
    if (tid < 384) {
      int p = tid - 256;
      float2 lm = ((const float2*)cb)[p];
      lamr = lm.x; lami = lm.y;
      size_t hoff = (((size_t)l * NB + b) * NP + p) * 2;
      hr = hidden[hoff]; hi = hidden[hoff + 1];
    }
  }
  __syncthreads();

#pragma unroll 1
  for (int i = 0; i < NCH + 2; ++i) {
    float yreg[4][4], xres[4][4];
    // ---------------- P1a ----------------
    if (tid < 256) {
      if (i < NCH) {
        float vv[16];
        *(float4*)&vv[0] = pre0;  *(float4*)&vv[4] = pre1;
        *(float4*)&vv[8] = pre2;  *(float4*)&vv[12] = pre3;
        int r = tid >> 2, q = tid & 3;
        if (i < NCH - 1) {
          const float* xr = x + ((size_t)b * NT + (i + 1) * CHL + r) * NH + q * 16;
          pre0 = *(const float4*)(xr);     pre1 = *(const float4*)(xr + 4);
          pre2 = *(const float4*)(xr + 8); pre3 = *(const float4*)(xr + 12);
        }
        float s = 0.f, s2 = 0.f;
#pragma unroll
        for (int j = 0; j < 16; ++j) { s += vv[j]; s2 += vv[j] * vv[j]; }
        s += __shfl_xor(s, 1); s2 += __shfl_xor(s2, 1);
        s += __shfl_xor(s, 2); s2 += __shfl_xor(s2, 2);
        float mu = s * 0.015625f;
        float var = s2 * 0.015625f - mu * mu;
        float rs = rsqrtf(var + 1e-6f);
        if (q == 0) { murs[i & 3][r][0] = mu; murs[i & 3][r][1] = rs; }
#pragma unroll
        for (int j = 0; j < 16; ++j)
          xnS[r][q * 16 + j] = f2b((vv[j] - mu) * rs * nscr[j] + nbir[j]);
      }
    } else if (i >= 2) {
      int j = i - 2, wv2 = wv - 4;
#pragma unroll
      for (int ct = 0; ct < 4; ++ct)
#pragma unroll
        for (int e = 0; e < 4; ++e) {
          int rl = wv2 * 16 + (lane >> 4) * 4 + e;
          xres[ct][e] = x[((size_t)b * NT + j * CHL + rl) * NH + ct * 16 + (lane & 15)];
        }
      f32x4 acc[4] = {};
      const unsigned short (*Bu)[264] = BuS[j & 1];
#pragma unroll
      for (int kc = 0; kc < 8; ++kc) {
        bf16x8 a = *(const bf16x8*)&Bu[wv2 * 16 + (lane & 15)][kc * 32 + (lane >> 4) * 8];
#pragma unroll
        for (int ct = 0; ct < 4; ++ct) {
          bf16x8 bbf = *(const bf16x8*)&Cs[ct * 16 + (lane & 15)][kc * 32 + (lane >> 4) * 8];
          acc[ct] = __builtin_amdgcn_mfma_f32_16x16x32_bf16(a, bbf, acc[ct], 0, 0, 0);
        }
      }
#pragma unroll
      for (int ct = 0; ct < 4; ++ct)
#pragma unroll
        for (int e = 0; e < 4; ++e) {
          int rl = wv2 * 16 + (lane >> 4) * 4 + e;
          float mu = murs[j & 3][rl][0], rs = murs[j & 3][rl][1];
          float xnv = (xres[ct][e] - mu) * rs * nscc[ct] + nbic[ct];
          float yv = acc[ct][e] + Dr[ct] * xnv;
          float t3 = 0.7978845608f * (yv + 0.044715f * yv * yv * yv);
          float u = __expf(2.f * t3);
          yv = 0.5f * yv * (2.f - 2.f / (u + 1.f));
          yreg[ct][e] = yv;
          Ys[rl][ct * 16 + (lane & 15)] = f2b(yv);
        }
    }
    __syncthreads();
    // ---------------- P1b ----------------
    if (tid >= 256 && i >= 2) {
      int j = i - 2, wv2 = wv - 4;
      f32x4 gacc[4] = {};
#pragma unroll
      for (int kc = 0; kc < 2; ++kc) {
        bf16x8 a = *(const bf16x8*)&Ys[wv2 * 16 + (lane & 15)][kc * 32 + (lane >> 4) * 8];
#pragma unroll
        for (int ct = 0; ct < 4; ++ct) {
          bf16x8 bbf = *(const bf16x8*)(gwT + (ct * 16 + (lane & 15)) * 64 + kc * 32 + (lane >> 4) * 8);
          gacc[ct] = __builtin_amdgcn_mfma_f32_16x16x32_bf16(a, bbf, gacc[ct], 0, 0, 0);
        }
      }
#pragma unroll
      for (int ct = 0; ct < 4; ++ct)
#pragma unroll
        for (int e = 0; e < 4; ++e) {
          int rl = wv2 * 16 + (lane >> 4) * 4 + e;
          float g = gacc[ct][e] + gbr[ct];
          float sg = 1.f / (1.f + __expf(-g));
          x[((size_t)b * NT + j * CHL + rl) * NH + ct * 16 + (lane & 15)] =
              xres[ct][e] + yreg[ct][e] * sg;
        }
    }
    __syncthreads();
    // ---------------- P2 ----------------
    if (tid < 256) {
      if (i < NCH) {
        f32x4 acc[16] = {};
#pragma unroll
        for (int kc = 0; kc < 2; ++kc) {
          bf16x8 a = *(const bf16x8*)&xnS[wv * 16 + (lane & 15)][kc * 32 + (lane >> 4) * 8];
#pragma unroll
          for (int ct = 0; ct < 16; ++ct) {
            bf16x8 bbf = *(const bf16x8*)&Bs[ct * 16 + (lane & 15)][kc * 32 + (lane >> 4) * 8];
            acc[ct] = __builtin_amdgcn_mfma_f32_16x16x32_bf16(a, bbf, acc[ct], 0, 0, 0);
          }
        }
        unsigned short (*Bu)[264] = BuS[i & 1];
#pragma unroll
        for (int ct = 0; ct < 16; ++ct)
#pragma unroll
          for (int e = 0; e < 4; ++e)
            Bu[wv * 16 + (lane >> 4) * 4 + e][ct * 16 + (lane & 15)] = f2b(acc[ct][e]);
      }
    } else if (tid < 384 && i >= 1 && i <= NCH) {
      int ch = i - 1, p = tid - 256;
      unsigned short (*Bu)[264] = BuS[ch & 1];
#pragma unroll 4
      for (int t = 0; t < CHL; ++t) {
        unsigned int u = *(const unsigned int*)&Bu[t][2 * p];
        float bur = b2f((unsigned short)(u & 0xffffu));
        float bui = b2f((unsigned short)(u >> 16));
        if (dS[ch * CHL + t]) { hr = bur; hi = bui; }
        else {
          float nr = lamr * hr - lami * hi + bur;
          hi = lamr * hi + lami * hr + bui; hr = nr;
        }
        *(unsigned int*)&Bu[t][2 * p] = (unsigned int)f2b(hr) | ((unsigned int)f2b(hi) << 16);
      }
      if (i == NCH) {
        size_t hoff = (((size_t)l * NB + b) * NP + p) * 2;
        hout[hoff] = hr; hout[hoff + 1] = hi;
      }
    }
    __syncthreads();
  }
}

extern "C" void kernel_launch(void* const* d_in, const int* in_sizes, int n_in,
                              void* d_out, int out_size, void* d_ws, size_t ws_size,
                              hipStream_t stream) {
  const float* obs    = (const float*)d_in[0];
  const int*   dones  = (const int*)d_in[1];
  const float* hidden = (const float*)d_in[2];
  const float* dw     = (const float*)d_in[3];
  const float* db     = (const float*)d_in[4];
  const float* Lre    = (const float*)d_in[5];
  const float* Lim    = (const float*)d_in[6];
  const float* Bp     = (const float*)d_in[7];
  const float* Cp     = (const float*)d_in[8];
  const float* Dv     = (const float*)d_in[9];
  const float* lstep  = (const float*)d_in[10];
  const float* nsc    = (const float*)d_in[11];
  const float* nbi    = (const float*)d_in[12];
  const float* gw     = (const float*)d_in[13];
  const float* gb     = (const float*)d_in[14];

  float* hout = (float*)d_out;
  float* x = hout + (size_t)2 * NB * NP * 2;   // 65536 floats offset

  unsigned char* wsb = (unsigned char*)d_ws;
  unsigned short* wTb = (unsigned short*)(wsb + WTB_OFF);

  k_setup<<<dim3(64, 2), 256, 0, stream>>>(Lre, Lim, Bp, Cp, lstep, gw, dw, wsb);
  k_dense<<<NM / 128, 256, 0, stream>>>(obs, wTb, db, x);
  for (int l = 0; l < 2; ++l) {
    const unsigned char* cb = wsb + CONST_OFF + (size_t)l * CONST_STRIDE;
    k_layer<<<NB, 512, 0, stream>>>(x, dones, cb, hidden, hout,
                                    nsc + l * NH, nbi + l * NH,
                                    Dv + l * NH, gb + l * NH, l);
  }
}

// Round 6
// 320.763 us; speedup vs baseline: 1.0795x; 1.0191x over previous
//
#include <hip/hip_runtime.h>

#define NB 128
#define NT 1024
#define NOBS 512
#define NH 64
#define NP 128
#define NM (NB*NT)      // 131072 rows
#define NN2 256
#define NCH 16
#define CHL 64

typedef short bf16x8 __attribute__((ext_vector_type(8)));
typedef float f32x4 __attribute__((ext_vector_type(4)));

// ---- ws layout (bytes) ----
#define CONST_OFF ((size_t)91226112)
#define CONST_STRIDE ((size_t)131072)
#define WTB_OFF   ((size_t)92274688)
// const block: [0,1024) lambar f32x2; [1024,33792) Bglob bf16 [256][64];
// [33792,66560) Cglob bf16 [64][256]; [66560,74752) gwT bf16 [64][64]

__device__ __forceinline__ unsigned short f2b(float f) {
  unsigned int u = __float_as_uint(f);
  u = u + 0x7fffu + ((u >> 16) & 1u);
  return (unsigned short)(u >> 16);
}
__device__ __forceinline__ float b2f(unsigned short s) {
  return __uint_as_float(((unsigned int)s) << 16);
}

// ---------------- setup: per-layer constant tables + dense W^T bf16 ----------------
__global__ __launch_bounds__(256) void k_setup(const float* Lre, const float* Lim,
    const float* Bp, const float* Cp, const float* lstep, const float* gw,
    const float* dw, unsigned char* wsb) {
  int l = blockIdx.y;
  int idx = blockIdx.x * 256 + threadIdx.x;   // [0,16384)
  unsigned char* cb = wsb + CONST_OFF + (size_t)l * CONST_STRIDE;
  float2* lambar = (float2*)cb;
  unsigned short* Bglob = (unsigned short*)(cb + 1024);
  unsigned short* Cglob = (unsigned short*)(cb + 33792);
  unsigned short* gwT   = (unsigned short*)(cb + 66560);
  {
    int n = idx >> 6, h = idx & 63, p = n >> 1, c = n & 1;
    float step = expf(lstep[l * NP + p]);
    float re = Lre[l * NP + p], im = Lim[l * NP + p];
    float er = expf(re * step), ang = im * step;
    float lbr = er * cosf(ang), lbi = er * sinf(ang);
    if (h == 0 && c == 0) lambar[p] = make_float2(lbr, lbi);
    float den = re * re + im * im;
    float nr = lbr - 1.f, ni = lbi;
    float dr = (nr * re + ni * im) / den;
    float di = (ni * re - nr * im) / den;
    size_t bb = ((size_t)(l * NP + p) * NH + h) * 2;
    float b0 = Bp[bb + 0], b1 = Bp[bb + 1];
    float vr = dr * b0 - di * b1;
    float vi = dr * b1 + di * b0;
    Bglob[n * 64 + h] = f2b(c ? vi : vr);
  }
  {
    int h = idx >> 8, n = idx & 255, p = n >> 1;
    size_t base = ((size_t)(l * NH + h) * NP + p) * 2;
    float val = (n & 1) ? (-2.f * Cp[base + 1]) : (2.f * Cp[base + 0]);
    Cglob[h * 256 + n] = f2b(val);
  }
  if (idx < 4096) {
    int n = idx >> 6, k = idx & 63;
    gwT[n * 64 + k] = f2b(gw[(size_t)(l * NH + k) * NH + n]);
  }
  {
    int idx2 = l * 16384 + idx;
    int h = idx2 >> 9, k = idx2 & 511;
    ((unsigned short*)(wsb + WTB_OFF))[h * 512 + k] = f2b(dw[(size_t)k * NH + h]);
  }
}

// ---------------- dense: x = obs @ W + b (pipelined, BK=64) ----------------
__global__ __launch_bounds__(256) void k_dense(const float* __restrict__ obs,
    const unsigned short* __restrict__ wTb, const float* __restrict__ bias,
    float* __restrict__ xout) {
  __shared__ __align__(16) unsigned short As[128][72];
  __shared__ __align__(16) unsigned short Bs[64][72];
  int tid = threadIdx.x, lane = tid & 63, wv = tid >> 6;
  int row0 = blockIdx.x * 128;
  f32x4 acc[2][4] = {};
  float bcol[4];
#pragma unroll
  for (int ct = 0; ct < 4; ++ct) bcol[ct] = bias[ct * 16 + (lane & 15)];
  float4 ra[8];
  uint4 rb[2];
#pragma unroll
  for (int i = 0; i < 8; ++i) {
    int id = tid + i * 256;
    ra[i] = *(const float4*)(obs + (size_t)(row0 + (id >> 4)) * NOBS + (id & 15) * 4);
  }
#pragma unroll
  for (int i = 0; i < 2; ++i) {
    int id = tid + i * 256;
    rb[i] = *(const uint4*)(wTb + (id >> 3) * 512 + (id & 7) * 8);
  }
  for (int kt = 0; kt < 8; ++kt) {
#pragma unroll
    for (int i = 0; i < 8; ++i) {
      int id = tid + i * 256;
      ushort4 o; o.x = f2b(ra[i].x); o.y = f2b(ra[i].y); o.z = f2b(ra[i].z); o.w = f2b(ra[i].w);
      *(ushort4*)&As[id >> 4][(id & 15) * 4] = o;
    }
#pragma unroll
    for (int i = 0; i < 2; ++i) {
      int id = tid + i * 256;
      *(uint4*)&Bs[id >> 3][(id & 7) * 8] = rb[i];
    }
    __syncthreads();
    if (kt < 7) {
      int k0 = (kt + 1) * 64;
#pragma unroll
      for (int i = 0; i < 8; ++i) {
        int id = tid + i * 256;
        ra[i] = *(const float4*)(obs + (size_t)(row0 + (id >> 4)) * NOBS + k0 + (id & 15) * 4);
      }
#pragma unroll
      for (int i = 0; i < 2; ++i) {
        int id = tid + i * 256;
        rb[i] = *(const uint4*)(wTb + (id >> 3) * 512 + k0 + (id & 7) * 8);
      }
    }
#pragma unroll
    for (int kc = 0; kc < 2; ++kc) {
      bf16x8 a0 = *(const bf16x8*)&As[wv * 32 + (lane & 15)][kc * 32 + (lane >> 4) * 8];
      bf16x8 a1 = *(const bf16x8*)&As[wv * 32 + 16 + (lane & 15)][kc * 32 + (lane >> 4) * 8];
#pragma unroll
      for (int ct = 0; ct < 4; ++ct) {
        bf16x8 bb = *(const bf16x8*)&Bs[ct * 16 + (lane & 15)][kc * 32 + (lane >> 4) * 8];
        acc[0][ct] = __builtin_amdgcn_mfma_f32_16x16x32_bf16(a0, bb, acc[0][ct], 0, 0, 0);
        acc[1][ct] = __builtin_amdgcn_mfma_f32_16x16x32_bf16(a1, bb, acc[1][ct], 0, 0, 0);
      }
    }
    __syncthreads();
  }
  float* Os = (float*)&As[0][0];   // [64][68]
#pragma unroll
  for (int pass = 0; pass < 2; ++pass) {
    if ((wv >> 1) == pass) {
#pragma unroll
      for (int rt = 0; rt < 2; ++rt)
#pragma unroll
        for (int ct = 0; ct < 4; ++ct)
#pragma unroll
          for (int e = 0; e < 4; ++e) {
            int rl = (wv & 1) * 32 + rt * 16 + (lane >> 4) * 4 + e;
            int col = ct * 16 + (lane & 15);
            Os[rl * 68 + col] = acc[rt][ct][e] + bcol[ct];
          }
    }
    __syncthreads();
    {
      int r = tid >> 2, seg = tid & 3;
#pragma unroll
      for (int i = 0; i < 4; ++i)
        *(float4*)(xout + (size_t)(row0 + pass * 64 + r) * NH + seg * 16 + i * 4) =
            *(const float4*)&Os[r * 68 + seg * 16 + i * 4];
    }
    __syncthreads();
  }
}

// ---------------- mega-fused BOTH-layers kernel ----------------
// 1 block per batch b, 512 threads; inner loop over l=0,1 (layers are per-b
// independent). Internals per layer identical to R5.
__global__ __launch_bounds__(512, 2) void k_2layers(float* __restrict__ x,
    const int* __restrict__ dones, const unsigned char* __restrict__ cb0,
    const float* __restrict__ hidden, float* __restrict__ hout,
    const float* __restrict__ nsc0, const float* __restrict__ nbi0,
    const float* __restrict__ Dv0, const float* __restrict__ gb0) {
  __shared__ __align__(16) unsigned short Bs[256][72];      // 36864
  __shared__ __align__(16) unsigned short Cs[64][264];      // 33792
  __shared__ __align__(16) unsigned short BuS[2][64][264];  // 67584
  __shared__ __align__(16) unsigned short xnS[64][72];      // 9216
  __shared__ __align__(16) unsigned short Ys[64][72];       // 9216
  __shared__ int dS[1024];                                  // 4096
  __shared__ float murs[4][64][2];                          // 2048  => 162816 B
  int tid = threadIdx.x, lane = tid & 63, wv = tid >> 6;
  int b = blockIdx.x;

  dS[tid] = dones[b * NT + tid];
  dS[tid + 512] = dones[b * NT + 512 + tid];

#pragma unroll 1
  for (int l = 0; l < 2; ++l) {
    const unsigned char* cb = cb0 + (size_t)l * CONST_STRIDE;
    const float* nsc = nsc0 + l * NH;
    const float* nbi = nbi0 + l * NH;
    const float* Dv  = Dv0 + l * NH;
    const float* gb  = gb0 + l * NH;
    const unsigned short* Bglob = (const unsigned short*)(cb + 1024);
    const unsigned short* Cglob = (const unsigned short*)(cb + 33792);
    const unsigned short* gwT = (const unsigned short*)(cb + 66560);

    // stage tables for this layer (previous iter ended with __syncthreads)
    {
      int r = tid >> 1, h0 = (tid & 1) * 32;
#pragma unroll
      for (int i = 0; i < 4; ++i)
        *(uint4*)&Bs[r][h0 + i * 8] = *(const uint4*)(Bglob + r * 64 + h0 + i * 8);
    }
    {
      int r = tid >> 3, s0 = (tid & 7) * 32;
#pragma unroll
      for (int i = 0; i < 4; ++i)
        *(uint4*)&Cs[r][s0 + i * 8] = *(const uint4*)(Cglob + r * 256 + s0 + i * 8);
    }

    // role preloads
    float4 pre0, pre1, pre2, pre3;
    float nscr[16], nbir[16];
    float lamr = 0.f, lami = 0.f, hr = 0.f, hi = 0.f;
    float Dr[4], nscc[4], nbic[4], gbr[4];
    if (tid < 256) {
      int q = tid & 3;
#pragma unroll
      for (int j = 0; j < 16; ++j) { nscr[j] = nsc[q * 16 + j]; nbir[j] = nbi[q * 16 + j]; }
      int r = tid >> 2;
      const float* xr = x + ((size_t)b * NT + r) * NH + q * 16;
      pre0 = *(const float4*)(xr);     pre1 = *(const float4*)(xr + 4);
      pre2 = *(const float4*)(xr + 8); pre3 = *(const float4*)(xr + 12);
    } else {
#pragma unroll
      for (int ct = 0; ct < 4; ++ct) {
        int col = ct * 16 + (lane & 15);
        Dr[ct] = Dv[col]; nscc[ct] = nsc[col]; nbic[ct] = nbi[col]; gbr[ct] = gb[col];
      }
      if (tid < 384) {
        int p = tid - 256;
        float2 lm = ((const float2*)cb)[p];
        lamr = lm.x; lami = lm.y;
        size_t hoff = (((size_t)l * NB + b) * NP + p) * 2;
        hr = hidden[hoff]; hi = hidden[hoff + 1];
      }
    }
    __syncthreads();

#pragma unroll 1
    for (int i = 0; i < NCH + 2; ++i) {
      float yreg[4][4], xres[4][4];
      // ---------------- P1a ----------------
      if (tid < 256) {
        if (i < NCH) {
          float vv[16];
          *(float4*)&vv[0] = pre0;  *(float4*)&vv[4] = pre1;
          *(float4*)&vv[8] = pre2;  *(float4*)&vv[12] = pre3;
          int r = tid >> 2, q = tid & 3;
          if (i < NCH - 1) {
            const float* xr = x + ((size_t)b * NT + (i + 1) * CHL + r) * NH + q * 16;
            pre0 = *(const float4*)(xr);     pre1 = *(const float4*)(xr + 4);
            pre2 = *(const float4*)(xr + 8); pre3 = *(const float4*)(xr + 12);
          }
          float s = 0.f, s2 = 0.f;
#pragma unroll
          for (int j = 0; j < 16; ++j) { s += vv[j]; s2 += vv[j] * vv[j]; }
          s += __shfl_xor(s, 1); s2 += __shfl_xor(s2, 1);
          s += __shfl_xor(s, 2); s2 += __shfl_xor(s2, 2);
          float mu = s * 0.015625f;
          float var = s2 * 0.015625f - mu * mu;
          float rs = rsqrtf(var + 1e-6f);
          if (q == 0) { murs[i & 3][r][0] = mu; murs[i & 3][r][1] = rs; }
#pragma unroll
          for (int j = 0; j < 16; ++j)
            xnS[r][q * 16 + j] = f2b((vv[j] - mu) * rs * nscr[j] + nbir[j]);
        }
      } else if (i >= 2) {
        int j = i - 2, wv2 = wv - 4;
#pragma unroll
        for (int ct = 0; ct < 4; ++ct)
#pragma unroll
          for (int e = 0; e < 4; ++e) {
            int rl = wv2 * 16 + (lane >> 4) * 4 + e;
            xres[ct][e] = x[((size_t)b * NT + j * CHL + rl) * NH + ct * 16 + (lane & 15)];
          }
        f32x4 acc[4] = {};
        const unsigned short (*Bu)[264] = BuS[j & 1];
#pragma unroll
        for (int kc = 0; kc < 8; ++kc) {
          bf16x8 a = *(const bf16x8*)&Bu[wv2 * 16 + (lane & 15)][kc * 32 + (lane >> 4) * 8];
#pragma unroll
          for (int ct = 0; ct < 4; ++ct) {
            bf16x8 bbf = *(const bf16x8*)&Cs[ct * 16 + (lane & 15)][kc * 32 + (lane >> 4) * 8];
            acc[ct] = __builtin_amdgcn_mfma_f32_16x16x32_bf16(a, bbf, acc[ct], 0, 0, 0);
          }
        }
#pragma unroll
        for (int ct = 0; ct < 4; ++ct)
#pragma unroll
          for (int e = 0; e < 4; ++e) {
            int rl = wv2 * 16 + (lane >> 4) * 4 + e;
            float mu = murs[j & 3][rl][0], rs = murs[j & 3][rl][1];
            float xnv = (xres[ct][e] - mu) * rs * nscc[ct] + nbic[ct];
            float yv = acc[ct][e] + Dr[ct] * xnv;
            float t3 = 0.7978845608f * (yv + 0.044715f * yv * yv * yv);
            float u = __expf(2.f * t3);
            yv = 0.5f * yv * (2.f - 2.f / (u + 1.f));
            yreg[ct][e] = yv;
            Ys[rl][ct * 16 + (lane & 15)] = f2b(yv);
          }
      }
      __syncthreads();
      // ---------------- P1b ----------------
      if (tid >= 256 && i >= 2) {
        int j = i - 2, wv2 = wv - 4;
        f32x4 gacc[4] = {};
#pragma unroll
        for (int kc = 0; kc < 2; ++kc) {
          bf16x8 a = *(const bf16x8*)&Ys[wv2 * 16 + (lane & 15)][kc * 32 + (lane >> 4) * 8];
#pragma unroll
          for (int ct = 0; ct < 4; ++ct) {
            bf16x8 bbf = *(const bf16x8*)(gwT + (ct * 16 + (lane & 15)) * 64 + kc * 32 + (lane >> 4) * 8);
            gacc[ct] = __builtin_amdgcn_mfma_f32_16x16x32_bf16(a, bbf, gacc[ct], 0, 0, 0);
          }
        }
#pragma unroll
        for (int ct = 0; ct < 4; ++ct)
#pragma unroll
          for (int e = 0; e < 4; ++e) {
            int rl = wv2 * 16 + (lane >> 4) * 4 + e;
            float g = gacc[ct][e] + gbr[ct];
            float sg = 1.f / (1.f + __expf(-g));
            x[((size_t)b * NT + j * CHL + rl) * NH + ct * 16 + (lane & 15)] =
                xres[ct][e] + yreg[ct][e] * sg;
          }
      }
      __syncthreads();
      // ---------------- P2 ----------------
      if (tid < 256) {
        if (i < NCH) {
          f32x4 acc[16] = {};
#pragma unroll
          for (int kc = 0; kc < 2; ++kc) {
            bf16x8 a = *(const bf16x8*)&xnS[wv * 16 + (lane & 15)][kc * 32 + (lane >> 4) * 8];
#pragma unroll
            for (int ct = 0; ct < 16; ++ct) {
              bf16x8 bbf = *(const bf16x8*)&Bs[ct * 16 + (lane & 15)][kc * 32 + (lane >> 4) * 8];
              acc[ct] = __builtin_amdgcn_mfma_f32_16x16x32_bf16(a, bbf, acc[ct], 0, 0, 0);
            }
          }
          unsigned short (*Bu)[264] = BuS[i & 1];
#pragma unroll
          for (int ct = 0; ct < 16; ++ct)
#pragma unroll
            for (int e = 0; e < 4; ++e)
              Bu[wv * 16 + (lane >> 4) * 4 + e][ct * 16 + (lane & 15)] = f2b(acc[ct][e]);
        }
      } else if (tid < 384 && i >= 1 && i <= NCH) {
        int ch = i - 1, p = tid - 256;
        unsigned short (*Bu)[264] = BuS[ch & 1];
#pragma unroll 4
        for (int t = 0; t < CHL; ++t) {
          unsigned int u = *(const unsigned int*)&Bu[t][2 * p];
          float bur = b2f((unsigned short)(u & 0xffffu));
          float bui = b2f((unsigned short)(u >> 16));
          if (dS[ch * CHL + t]) { hr = bur; hi = bui; }
          else {
            float nr = lamr * hr - lami * hi + bur;
            hi = lamr * hi + lami * hr + bui; hr = nr;
          }
          *(unsigned int*)&Bu[t][2 * p] = (unsigned int)f2b(hr) | ((unsigned int)f2b(hi) << 16);
        }
        if (i == NCH) {
          size_t hoff = (((size_t)l * NB + b) * NP + p) * 2;
          hout[hoff] = hr; hout[hoff + 1] = hi;
        }
      }
      __syncthreads();
    }
  }
}

extern "C" void kernel_launch(void* const* d_in, const int* in_sizes, int n_in,
                              void* d_out, int out_size, void* d_ws, size_t ws_size,
                              hipStream_t stream) {
  const float* obs    = (const float*)d_in[0];
  const int*   dones  = (const int*)d_in[1];
  const float* hidden = (const float*)d_in[2];
  const float* dw     = (const float*)d_in[3];
  const float* db     = (const float*)d_in[4];
  const float* Lre    = (const float*)d_in[5];
  const float* Lim    = (const float*)d_in[6];
  const float* Bp     = (const float*)d_in[7];
  const float* Cp     = (const float*)d_in[8];
  const float* Dv     = (const float*)d_in[9];
  const float* lstep  = (const float*)d_in[10];
  const float* nsc    = (const float*)d_in[11];
  const float* nbi    = (const float*)d_in[12];
  const float* gw     = (const float*)d_in[13];
  const float* gb     = (const float*)d_in[14];

  float* hout = (float*)d_out;
  float* x = hout + (size_t)2 * NB * NP * 2;   // 65536 floats offset

  unsigned char* wsb = (unsigned char*)d_ws;
  unsigned short* wTb = (unsigned short*)(wsb + WTB_OFF);

  k_setup<<<dim3(64, 2), 256, 0, stream>>>(Lre, Lim, Bp, Cp, lstep, gw, dw, wsb);
  k_dense<<<NM / 128, 256, 0, stream>>>(obs, wTb, db, x);
  k_2layers<<<NB, 512, 0, stream>>>(x, dones, wsb + CONST_OFF, hidden, hout,
                                    nsc, nbi, Dv, gb);
}